// Round 15
// baseline (72.070 us; speedup 1.0000x reference)
//
#include <hip/hip_runtime.h>
#include <hip/hip_fp16.h>

#define HH 128
#define WW 128
#define CIN 128
#define COUT 256
#define K9 9
#define HW (HH*WW)          // 16384
#define PIX (2*HW)          // 32768
#define KDIM (CIN*K9)       // 1152
#define BN_EPS 1e-5f
#define WROWS 7

typedef __attribute__((ext_vector_type(8))) short short8;
typedef __attribute__((ext_vector_type(4))) float f32x4;
typedef _Float16 half8 __attribute__((ext_vector_type(8)));
typedef unsigned short u16;
typedef unsigned int u32;

union H8 { short8 s; __half2 h2[4]; half8 h; };

// 16B sampling metadata: 4 clamped hw-indices (u16) + 4 premultiplied bilinear
// weights (f16, mask & validity folded in). Lives in LDS only.
struct __align__(16) Meta16 { ushort4 idx; __half2 w01, w23; };
static_assert(sizeof(Meta16) == 16, "");

__device__ __forceinline__ u16 f2h(float f) {
    union { __half h; u16 u; } x; x.h = __float2half_rn(f); return x.u;
}
__device__ __forceinline__ int swz(int px) { return (px & 3) ^ ((px >> 2) & 3); }

// ---------------------------------------------------------------------------
// prep_all: ONE launch for all preprocessing.
//   blocks [0,1024):   x [B][C][HW] f32 -> xt [B][HW][C] f16 (LDS transpose)
//   blocks [1024,2320): wT3/wOffT3 f16 transposes, cg-major subtile order:
//     q = (c>>5)*9 + k;  wT3[q][o][32ch], wOffT3[q][j][32ch]
// ---------------------------------------------------------------------------
__global__ __launch_bounds__(256) void prep_all(
    const float* __restrict__ x, const float* __restrict__ w_dcn,
    const float* __restrict__ w_off, u16* __restrict__ xt,
    u16* __restrict__ wT3, u16* __restrict__ wOffT3)
{
    __shared__ float tile[32][129];
    if (blockIdx.x < 1024) {
        const int b   = blockIdx.x >> 9;
        const int hw0 = (blockIdx.x & 511) * 32;
        const float* __restrict__ xb = x + (size_t)b * (CIN*HW);
        #pragma unroll
        for (int i = 0; i < 16; ++i) {
            const int idx = threadIdx.x + i*256;
            const int c = idx >> 5, hwl = idx & 31;
            tile[hwl][c] = xb[(size_t)c*HW + hw0 + hwl];
        }
        __syncthreads();
        const int hwl = threadIdx.x >> 3;
        const int c0  = (threadIdx.x & 7) * 16;
        short8 s0, s1;
        #pragma unroll
        for (int j = 0; j < 8; ++j) {
            s0[j] = (short)f2h(tile[hwl][c0 + j]);
            s1[j] = (short)f2h(tile[hwl][c0 + 8 + j]);
        }
        u16* dst = xt + ((size_t)b*HW + hw0 + hwl)*CIN + c0;
        *(short8*)dst = s0;
        *(short8*)(dst + 8) = s1;
    } else {
        const int u2 = (blockIdx.x - 1024) * 2 + (threadIdx.x >> 7);  // < 2592
        const int c  = threadIdx.x & 127;
        const int k  = u2 % 9;
        const int o  = u2 / 9;           // 0..287
        const int q  = (c >> 5)*9 + k;   // cg-major subtile
        const int ch = c & 31;
        if (o < COUT) {
            wT3[((size_t)q*COUT + o)*32 + ch] =
                f2h(w_dcn[(size_t)o*KDIM + c*K9 + k]);
        } else {
            const int j = o - COUT;
            wOffT3[((size_t)q*32 + j)*32 + ch] =
                (j < 27) ? f2h(w_off[(size_t)j*KDIM + c*K9 + k]) : (u16)0;
        }
    }
}

// ---------------------------------------------------------------------------
// dcn_fused: offs-conv (MFMA, meta->LDS) + WINDOWED implicit GEMM.
// 512 thr = 8 waves, 64 px (half an image row -> all px share row h).
// Main loop is cg-major (4 groups of 32 ch): per cg, stage a 7-row x 128-col
// x 32-ch LDS window (dense global loads), then all bilinear corner reads are
// ds_reads (per-lane clamp-checked global fallback for out-of-window rows).
// Combine (256 thr) -> Vs[k&1] (4KB, XOR-swizzled); 8 waves MFMA over it.
// Kills the TCP scattered-request wall (302 MB scatter -> ~30 MB dense).
// ---------------------------------------------------------------------------
__global__ __launch_bounds__(512, 4) __attribute__((amdgpu_waves_per_eu(4, 4)))
void dcn_fused(
    const u16* __restrict__ xt, const u16* __restrict__ wT3,
    const u16* __restrict__ wOffT3, const float* __restrict__ b_off,
    const float* __restrict__ b_dcn, const float* __restrict__ gamma,
    const float* __restrict__ beta, const float* __restrict__ mmean,
    const float* __restrict__ mvar, float* __restrict__ out)
{
    __shared__ __align__(16) u16 win[WROWS*128*4*8];   // 57344 B window
    __shared__ __align__(16) u16 Vs[2][64*4*8];        //  8192 B B-tiles
    __shared__ __align__(16) Meta16 metaL[K9*64];      //  9216 B

    const int t = threadIdx.x, l = t & 63, wv = t >> 6;   // wv 0..7
    const int l15 = l & 15, lq = l >> 4;
    const int bid = (blockIdx.x & 7) * 64 + (blockIdx.x >> 3);  // 512 blocks
    const int pg0 = bid * 64;
    const int b   = pg0 >> 14;
    const int hw0 = pg0 & 16383;
    const int hrow = hw0 >> 7;                 // shared row of all 64 px
    const int wlo  = min(max(hrow - 3, 0), HH - WROWS);
    const u16* __restrict__ xtb = xt + (size_t)b * (HW*CIN);

    // ================= phase -1: offsets conv + meta build =================
    {
        const int pxg = wv & 3;           // px group 0..3 (16 px)
        const int ks  = wv >> 2;          // k-segment: q in [18ks, 18ks+18)
        const int px  = pxg*16 + l15;     // 0..63
        const int hw  = (pg0 + px) & 16383;
        const int h = hw >> 7, w = hw & 127;
        f32x4 oa0 = {0.f,0.f,0.f,0.f}, oa1 = {0.f,0.f,0.f,0.f};
        #pragma unroll
        for (int it = 0; it < 18; ++it) {
            const int q  = ks*18 + it;            // subtile: cg = q/9, k = q%9
            const int cg = 2*ks + (it / 9);
            const int k  = it % 9;
            const int c0 = cg * 32;
            const int yy = h + (k/3) - 1, xx = w + (k%3) - 1;
            const bool valid = ((unsigned)yy < HH) && ((unsigned)xx < WW);
            const int idx = min(max(yy,0),HH-1)*WW + min(max(xx,0),WW-1);
            H8 bv, a0, a1;
            bv.s = *(const short8*)(xtb + (size_t)idx*CIN + c0 + lq*8);
            a0.s = *(const short8*)(wOffT3 + ((size_t)q*32 + l15)*32      + lq*8);
            a1.s = *(const short8*)(wOffT3 + ((size_t)q*32 + 16 + l15)*32 + lq*8);
            if (!valid) bv.s = (short8){0,0,0,0,0,0,0,0};
            oa0 = __builtin_amdgcn_mfma_f32_16x16x32_f16(a0.h, bv.h, oa0, 0,0,0);
            oa1 = __builtin_amdgcn_mfma_f32_16x16x32_f16(a1.h, bv.h, oa1, 0,0,0);
        }
        float* plane = (float*)win + ks * (64*33);
        #pragma unroll
        for (int r = 0; r < 4; ++r) {
            plane[px*33 + lq*4 + r]      = oa0[r];
            plane[px*33 + 16 + lq*4 + r] = oa1[r];
        }
        __syncthreads();

        const float* __restrict__ p0 = (const float*)win;
        const float* __restrict__ p1 = (const float*)win + 64*33;
        #pragma unroll
        for (int rd = 0; rd < 2; ++rd) {
            const int u = t + rd*512;
            if (u < 576) {
                const int px2 = u & 63, k = u >> 6;
                const int hwp = (pg0 + px2) & 16383;
                const int hp = hwp >> 7, wp = hwp & 127;
                const float dy = p0[px2*33 + 2*k]     + p1[px2*33 + 2*k]     + b_off[2*k];
                const float dx = p0[px2*33 + 2*k + 1] + p1[px2*33 + 2*k + 1] + b_off[2*k+1];
                const float mm = p0[px2*33 + 18 + k]  + p1[px2*33 + 18 + k]  + b_off[18+k];
                const float py = (float)hp + (float)(k/3) - 1.0f + dy;
                const float px_ = (float)wp + (float)(k%3) - 1.0f + dx;
                const float msk = 1.0f / (1.0f + expf(-mm));
                const float y0f = floorf(py), x0f = floorf(px_);
                const float wy = py - y0f, wx = px_ - x0f;
                const int y0 = (int)y0f, x0 = (int)x0f;
                const int y1 = y0 + 1,   x1 = x0 + 1;
                const bool v00 = ((unsigned)y0 < HH) && ((unsigned)x0 < WW);
                const bool v01 = ((unsigned)y0 < HH) && ((unsigned)x1 < WW);
                const bool v10 = ((unsigned)y1 < HH) && ((unsigned)x0 < WW);
                const bool v11 = ((unsigned)y1 < HH) && ((unsigned)x1 < WW);
                const int y0c = min(max(y0,0),HH-1), y1c = min(max(y1,0),HH-1);
                const int x0c = min(max(x0,0),WW-1), x1c = min(max(x1,0),WW-1);
                Meta16 mo;
                mo.idx.x = (u16)(y0c*WW + x0c);
                mo.idx.y = (u16)(y0c*WW + x1c);
                mo.idx.z = (u16)(y1c*WW + x0c);
                mo.idx.w = (u16)(y1c*WW + x1c);
                const float f00 = v00 ? (1.f-wy)*(1.f-wx)*msk : 0.f;
                const float f01 = v01 ? (1.f-wy)*wx*msk       : 0.f;
                const float f10 = v10 ? wy*(1.f-wx)*msk       : 0.f;
                const float f11 = v11 ? wy*wx*msk             : 0.f;
                mo.w01 = __floats2half2_rn(f00, f01);
                mo.w23 = __floats2half2_rn(f10, f11);
                metaL[k*64 + px2] = mo;
            }
        }
        __syncthreads();   // metaL ready; planes (win alias) dead
    }

    // ================= main GEMM: windowed, cg-major =================
    const int pxs = t >> 2;            // staging/combine px 0..127 / 0..63
    const int chl = t & 3;             // 16B chunk within 32ch

    f32x4 acc[8];                      // acc[m*4+n], m<2, n<4
    #pragma unroll
    for (int i = 0; i < 8; ++i) acc[i] = (f32x4){0.f,0.f,0.f,0.f};

// stage one window row i (all 512 threads): dense 16B global -> swizzled LDS
#define WLD(dst_, i_) \
    dst_.s = *(const short8*)(xtb + (size_t)((wlo + (i_))*WW + pxs)*CIN \
                              + cg*32 + chl*8)
#define WWR(i_, v_) \
    *(short8*)&win[(((i_)*128 + pxs)*4 + (chl ^ swz(pxs)))*8] = v_.s

// combine (px, 16B-chunk) for tap k -> Vs[buf]; threads t<256 only
#define COMBINE(k_, buf_) do { \
    if (t < 256) { \
        const Meta16 mt_ = metaL[(k_)*64 + pxs]; \
        const __half2 wb0_ = __half2half2(__low2half(mt_.w01)); \
        const __half2 wb1_ = __half2half2(__high2half(mt_.w01)); \
        const __half2 wb2_ = __half2half2(__low2half(mt_.w23)); \
        const __half2 wb3_ = __half2half2(__high2half(mt_.w23)); \
        H8 c_[4]; \
        const int hwv_[4] = { mt_.idx.x, mt_.idx.y, mt_.idx.z, mt_.idx.w }; \
        _Pragma("unroll") \
        for (int j_ = 0; j_ < 4; ++j_) { \
            const int y_ = hwv_[j_] >> 7, x_ = hwv_[j_] & 127; \
            const int yr_ = y_ - wlo; \
            if ((unsigned)yr_ < (unsigned)WROWS) { \
                c_[j_].s = *(const short8*)&win[((yr_*128 + x_)*4 \
                                                + (chl ^ swz(x_)))*8]; \
            } else { \
                c_[j_].s = *(const short8*)(xtb + (size_t)hwv_[j_]*CIN \
                                            + cg*32 + chl*8); \
            } \
        } \
        H8 r_; \
        _Pragma("unroll") \
        for (int i_ = 0; i_ < 4; ++i_) \
            r_.h2[i_] = __hfma2(c_[3].h2[i_], wb3_, \
                        __hfma2(c_[2].h2[i_], wb2_, \
                        __hfma2(c_[1].h2[i_], wb1_, \
                        __hmul2(c_[0].h2[i_], wb0_)))); \
        *(short8*)&Vs[buf_][(pxs*4 + (chl ^ swz(pxs)))*8] = r_.s; \
    } \
} while (0)

    for (int cg = 0; cg < 4; ++cg) {
        // ---- stage window(cg): 7 rows, dense ----
        {
            H8 s0, s1, s2, s3;
            WLD(s0, 0); WLD(s1, 1); WLD(s2, 2); WLD(s3, 3);
            WWR(0, s0); WWR(1, s1); WWR(2, s2); WWR(3, s3);
            WLD(s0, 4); WLD(s1, 5); WLD(s2, 6);
            WWR(4, s0); WWR(5, s1); WWR(6, s2);
        }
        __syncthreads();
        COMBINE(0, 0);
        __syncthreads();

        for (int k = 0; k < 9; ++k) {
            // A-frags for subtile q = cg*9+k
            H8 av[2];
            #pragma unroll
            for (int m = 0; m < 2; ++m)
                av[m].s = *(const short8*)
                    (wT3 + ((size_t)(cg*9 + k)*COUT + wv*32 + m*16 + l15)*32 + lq*8);

            // B-frags from Vs[k&1] + 8 MFMA
            H8 bf[4];
            #pragma unroll
            for (int n = 0; n < 4; ++n) {
                const int px = n*16 + l15;
                bf[n].s = *(const short8*)&Vs[k & 1][(px*4 + (lq ^ swz(px)))*8];
            }
            #pragma unroll
            for (int m = 0; m < 2; ++m)
                #pragma unroll
                for (int n = 0; n < 4; ++n)
                    acc[m*4 + n] = __builtin_amdgcn_mfma_f32_16x16x32_f16(
                                       av[m].h, bf[n].h, acc[m*4 + n], 0, 0, 0);

            if (k < 8) COMBINE(k + 1, (k + 1) & 1);
            __syncthreads();
        }
    }
#undef WLD
#undef WWR
#undef COMBINE

    // ---- epilogue: bias + BN + ReLU, coalesced stores ----
    #pragma unroll
    for (int m = 0; m < 2; ++m) {
        #pragma unroll
        for (int r = 0; r < 4; ++r) {
            const int o = wv*32 + m*16 + lq*4 + r;
            const float sc = gamma[o] * rsqrtf(mvar[o] + BN_EPS);
            const float sh = (b_dcn[o] - mmean[o]) * sc + beta[o];
            float* __restrict__ op = out + ((size_t)(b*COUT + o) << 14) + hw0;
            #pragma unroll
            for (int n = 0; n < 4; ++n) {
                const float v = fmaf(acc[m*4 + n][r], sc, sh);
                op[n*16 + l15] = fmaxf(v, 0.f);
            }
        }
    }
}

extern "C" void kernel_launch(void* const* d_in, const int* in_sizes, int n_in,
                              void* d_out, int out_size, void* d_ws, size_t ws_size,
                              hipStream_t stream) {
    (void)in_sizes; (void)n_in; (void)out_size; (void)ws_size;
    const float* x      = (const float*)d_in[0];
    const float* w_off  = (const float*)d_in[1];
    const float* b_off  = (const float*)d_in[2];
    const float* w_dcn  = (const float*)d_in[3];
    const float* b_dcn  = (const float*)d_in[4];
    const float* gamma  = (const float*)d_in[5];
    const float* beta   = (const float*)d_in[6];
    const float* mmean  = (const float*)d_in[7];
    const float* mvar   = (const float*)d_in[8];
    float* out = (float*)d_out;

    char* ws = (char*)d_ws;
    u16* xtp    = (u16*)ws;                          // 8,388,608 B
    u16* wT3    = (u16*)(ws + 8388608);              //   589,824 B
    u16* wOffT3 = (u16*)(ws + 8388608 + 589824);     //    73,728 B

    prep_all <<<dim3(1024 + 1296), 256, 0, stream>>>(x, w_dcn, w_off,
                                                     xtp, wT3, wOffT3);
    dcn_fused<<<dim3(PIX/64), 512, 0, stream>>>(xtp, wT3, wOffT3, b_off, b_dcn,
                                                gamma, beta, mmean, mvar, out);
}